// Round 9
// baseline (161.183 us; speedup 1.0000x reference)
//
#include <hip/hip_runtime.h>
#include <hip/hip_bf16.h>

typedef __bf16    bf16x8 __attribute__((ext_vector_type(8)));
typedef __bf16    bf16x4 __attribute__((ext_vector_type(4)));
typedef _Float16  f16x8  __attribute__((ext_vector_type(8)));
typedef _Float16  f16x4  __attribute__((ext_vector_type(4)));
typedef float     f32x4  __attribute__((ext_vector_type(4)));

#define HL 50
#define DD 64

// ============================ ALGORITHM =================================
// R15: fused GEMM1+GEMM2 main over f16 tables (R14 structure) with two
// fixes from R14's counters (occ 23.6%, LDS 36KB, prep ~30us):
//  (a) PER-MT LDS REPACK: h1 tile mt is self-contained (rows written
//      mt*16+quad*4+r == rows read mt*16+lq), so each wave reuses ONE
//      16x72 slice across the 4 tiles.  LDS/block 36864 -> 9216 B;
//      residency 2 -> 4 blocks/CU.  launch_bounds(256,4), cap 128 VGPR —
//      wide margin over ~70 live (no spill => no graph-capture death).
//  (b) cvt stream at full width: 2x float4 load + f16x8 16B store.
// h1 = relu(A16[va]@W1a + F16[af]@W1f + ba[node]), ba = b1 + rep@W1mid.
// A16 doubles as e_va table for the weighted-sum tail.

// ---- prep: [0,GC) cvt stream | [GC,GC+GB) bias | last: frag combos ----
__global__ __launch_bounds__(256, 4) void prep_all_kernel(
    const int*   __restrict__ nodes,
    const float* __restrict__ v2e,
    const float* __restrict__ a2e,
    const float* __restrict__ f2e,
    const float* __restrict__ W1,
    const float* __restrict__ b1,
    const float* __restrict__ W2,
    const float* __restrict__ b2,
    const float* __restrict__ w3,
    _Float16* __restrict__ A16, _Float16* __restrict__ F16,
    _Float16* __restrict__ ba16,
    _Float16* __restrict__ wf, float* __restrict__ wsc,
    int nA, int nF, int N, int GC, int GB)
{
    __shared__ __align__(16) _Float16 es[64 * 72];    // 9216 B (bias branch)
    const int tid  = threadIdx.x;
    const int w    = tid >> 6, lane = tid & 63;
    const int lq   = lane & 15, quad = lane >> 4;
    const int bid  = blockIdx.x;

    if (bid < GC) {
        // ---- streaming cvt f32->f16: 8 floats/thread/iter, 16B stores ----
        const size_t total = (size_t)(nA + nF) * 8;    // 8-float chunks
        for (size_t c = (size_t)bid * 256 + tid; c < total;
             c += (size_t)GC * 256) {
            const size_t row = c >> 3;
            const int    seg = (int)(c & 7);
            const float* s;
            _Float16*    d;
            if (row < (size_t)nA) {
                s = a2e + row * DD + seg * 8;
                d = A16 + row * DD + seg * 8;
            } else {
                const size_t r2 = row - (size_t)nA;
                s = f2e + r2 * DD + seg * 8;
                d = F16 + r2 * DD + seg * 8;
            }
            float4 v0 = *(const float4*)s;
            float4 v1 = *(const float4*)(s + 4);
            f16x8 pk = {(_Float16)v0.x, (_Float16)v0.y, (_Float16)v0.z, (_Float16)v0.w,
                        (_Float16)v1.x, (_Float16)v1.y, (_Float16)v1.z, (_Float16)v1.w};
            *(f16x8*)d = pk;
        }
    } else if (bid < GC + GB) {
        // ---- bias branch: ba16[n][c] = f16(b1[c] + rep_n . W1[64:128, c]) ----
        const int col = w * 16 + lq;
        const int n0 = (bid - GC) * 64;
        #pragma unroll
        for (int i = 0; i < 4; ++i) {
            int t = i * 256 + tid;
            int row = t >> 4, q = t & 15;
            int gn = n0 + row; if (gn >= N) gn = N - 1;
            int idx = nodes[gn];
            float4 v = *(const float4*)(v2e + (size_t)idx * DD + q * 4);
            f16x4 pk = {(_Float16)v.x, (_Float16)v.y, (_Float16)v.z, (_Float16)v.w};
            *(f16x4*)&es[row * 72 + q * 4] = pk;
        }
        f16x8 bfr[2];
        #pragma unroll
        for (int t = 0; t < 2; ++t)
            #pragma unroll
            for (int j = 0; j < 8; ++j)
                bfr[t][j] = (_Float16)W1[(64 + t * 32 + quad * 8 + j) * DD + col];
        const float b1c = b1[col];
        __syncthreads();

        f32x4 acc[4];
        #pragma unroll
        for (int mt = 0; mt < 4; ++mt) acc[mt] = (f32x4){0.f, 0.f, 0.f, 0.f};
        #pragma unroll
        for (int t = 0; t < 2; ++t)
            #pragma unroll
            for (int mt = 0; mt < 4; ++mt) {
                f16x8 a = *(const f16x8*)&es[(mt * 16 + lq) * 72 + t * 32 + quad * 8];
                acc[mt] = __builtin_amdgcn_mfma_f32_16x16x32_f16(a, bfr[t], acc[mt], 0, 0, 0);
            }
        #pragma unroll
        for (int mt = 0; mt < 4; ++mt)
            #pragma unroll
            for (int r = 0; r < 4; ++r) {
                int gn = n0 + mt * 16 + quad * 4 + r;
                if (gn < N) ba16[(size_t)gn * DD + col] = (_Float16)(acc[mt][r] + b1c);
            }
    } else {
        // ---- frag branch: 24 combos.  c<8: W1[0:64) (a-part); c in [8,16):
        // W1[128:192) (f-part); c in [16,24): W2.  Layout = MFMA B-frag.
        const int ln = tid & 63, c0 = tid >> 6;
        #pragma unroll
        for (int h = 0; h < 6; ++h) {
            int c = c0 + 4 * h;              // 0..23
            int part = c >> 3, cc = c & 7;
            int ct = cc >> 1, t = cc & 1;
            const float* S = (part == 2) ? W2 : W1;
            int koff = (part == 1) ? 128 : 0;
            _Float16* d = wf + ((size_t)c * 64 + ln) * 8;
            #pragma unroll
            for (int j = 0; j < 8; ++j)
                d[j] = (_Float16)S[(koff + t * 32 + (ln >> 4) * 8 + j) * DD
                                   + ct * 16 + (ln & 15)];
        }
        if (tid < 64) { wsc[tid] = w3[tid]; wsc[64 + tid] = b2[tid]; }
    }
}

// ---- main: ONE NODE PER WAVE, fused GEMM1+GEMM2, per-mt LDS slice ----
__global__ __launch_bounds__(256, 4) void va_main_kernel(
    const int*      __restrict__ hva,
    const int*      __restrict__ haf,
    const _Float16* __restrict__ A16,
    const _Float16* __restrict__ F16,
    const _Float16* __restrict__ ba16,
    const _Float16* __restrict__ wf,
    const float*    __restrict__ wsc,
    float*          __restrict__ out, int Ntot)
{
    __shared__ __align__(16) _Float16 hs[4][16 * 72];   // 9216 B, wave-private
    const int tid  = threadIdx.x;
    const int w    = tid >> 6;
    const int lane = tid & 63;
    const int lq   = lane & 15;
    const int quad = lane >> 4;
    const int node = blockIdx.x * 4 + w;
    if (node >= Ntot) return;
    _Float16* ws_ = hs[w];

    const int* hb = hva + node * HL;
    const int* fb = haf + node * HL;
    const int lclamp = (lane < HL) ? lane : 0;
    const int iv  = hb[lclamp];                 // lane l holds hva[l]
    const int ifv = fb[lclamp];                 // lane l holds haf[l]

    // ---- burst-gather f16 A16/F16 rows for A-fragments (2x f16x8/row) ----
    f16x8 xa[4][2], xf[4][2];
    #pragma unroll
    for (int mt = 0; mt < 4; ++mt) {
        const int row = mt * 16 + lq;
        const int ia  = __shfl(iv,  row);
        const int ifm = __shfl(ifv, row);
        #pragma unroll
        for (int t = 0; t < 2; ++t) {
            xa[mt][t] = *(const f16x8*)(A16 + (size_t)ia  * DD + t * 32 + quad * 8);
            xf[mt][t] = *(const f16x8*)(F16 + (size_t)ifm * DD + t * 32 + quad * 8);
        }
    }

    // ---- node-uniform bias values ----
    float bav[4];
    #pragma unroll
    for (int ct = 0; ct < 4; ++ct)
        bav[ct] = (float)ba16[(size_t)node * DD + ct * 16 + lq];

    // ---- per-mt: GEMM1 (16 MFMA) -> relu -> slice repack -> A-frag read ----
    f16x8 h1f[4][2];
    #pragma unroll
    for (int mt = 0; mt < 4; ++mt) {
        f32x4 acc[4];
        #pragma unroll
        for (int ct = 0; ct < 4; ++ct)
            acc[ct] = (f32x4){bav[ct], bav[ct], bav[ct], bav[ct]};
        #pragma unroll
        for (int ct = 0; ct < 4; ++ct)
            #pragma unroll
            for (int t = 0; t < 2; ++t) {
                f16x8 bfr = *(const f16x8*)(wf + ((size_t)(ct * 2 + t) * 64 + lane) * 8);
                acc[ct] = __builtin_amdgcn_mfma_f32_16x16x32_f16(xa[mt][t], bfr, acc[ct], 0, 0, 0);
            }
        #pragma unroll
        for (int ct = 0; ct < 4; ++ct)
            #pragma unroll
            for (int t = 0; t < 2; ++t) {
                f16x8 bfr = *(const f16x8*)(wf + ((size_t)(8 + ct * 2 + t) * 64 + lane) * 8);
                acc[ct] = __builtin_amdgcn_mfma_f32_16x16x32_f16(xf[mt][t], bfr, acc[ct], 0, 0, 0);
            }
        // relu + repack rows mt*16+quad*4+r into slice rows quad*4+r
        #pragma unroll
        for (int ct = 0; ct < 4; ++ct)
            #pragma unroll
            for (int r = 0; r < 4; ++r) {
                const int grow = mt * 16 + quad * 4 + r;
                float hv = (grow < HL) ? fmaxf(acc[ct][r], 0.f) : 0.f;
                ws_[(quad * 4 + r) * 72 + ct * 16 + lq] = (_Float16)hv;
            }
        // read back as GEMM2 A-fragments (slice row = lq)
        #pragma unroll
        for (int t = 0; t < 2; ++t)
            h1f[mt][t] = *(const f16x8*)&ws_[lq * 72 + t * 32 + quad * 8];
    }

    // ---- GEMM2 (4 col-tiles x 2 K) + score partials ----
    float sc[4][4];
    #pragma unroll
    for (int mt = 0; mt < 4; ++mt)
        #pragma unroll
        for (int r = 0; r < 4; ++r) sc[mt][r] = 0.f;

    #pragma unroll
    for (int ct = 0; ct < 4; ++ct) {
        const float b2c = wsc[64 + ct * 16 + lq];
        const float w3c = wsc[ct * 16 + lq];
        f16x8 bfr[2];
        #pragma unroll
        for (int t = 0; t < 2; ++t)
            bfr[t] = *(const f16x8*)(wf + ((size_t)(16 + ct * 2 + t) * 64 + lane) * 8);
        #pragma unroll
        for (int mt = 0; mt < 4; ++mt) {
            f32x4 a2 = {b2c, b2c, b2c, b2c};
            #pragma unroll
            for (int t = 0; t < 2; ++t)
                a2 = __builtin_amdgcn_mfma_f32_16x16x32_f16(h1f[mt][t], bfr[t], a2, 0, 0, 0);
            #pragma unroll
            for (int r = 0; r < 4; ++r)
                sc[mt][r] = fmaf(fmaxf(a2[r], 0.f), w3c, sc[mt][r]);
        }
    }

    // ---- reduce scores over lq (each lane then holds its quad's 16 rows) ----
    #pragma unroll
    for (int mt = 0; mt < 4; ++mt)
        #pragma unroll
        for (int r = 0; r < 4; ++r)
            #pragma unroll
            for (int m = 1; m < 16; m <<= 1)
                sc[mt][r] += __shfl_xor(sc[mt][r], m);

    // ---- in-register softmax over 50 rows (row = mt*16 + quad*4 + r) ----
    #pragma unroll
    for (int r = 0; r < 4; ++r)
        if (48 + quad * 4 + r >= HL) sc[3][r] = -3.0e38f;   // rows 50..63

    float mx = sc[0][0];
    #pragma unroll
    for (int mt = 0; mt < 4; ++mt)
        #pragma unroll
        for (int r = 0; r < 4; ++r) mx = fmaxf(mx, sc[mt][r]);
    mx = fmaxf(mx, __shfl_xor(mx, 16));
    mx = fmaxf(mx, __shfl_xor(mx, 32));

    float sm = 0.f;
    #pragma unroll
    for (int mt = 0; mt < 4; ++mt)
        #pragma unroll
        for (int r = 0; r < 4; ++r) {
            sc[mt][r] = __expf(sc[mt][r] - mx);             // 0 for invalid rows
            sm += sc[mt][r];
        }
    sm += __shfl_xor(sm, 16);
    sm += __shfl_xor(sm, 32);
    const float inv = 1.f / sm;

    // ---- weighted e_va sum from A16 (rows L2-hot from GEMM1 gather) ----
    float oa[4] = {0.f, 0.f, 0.f, 0.f};
    #pragma unroll
    for (int l = 0; l < HL; ++l) {
        const int   srcl = ((l >> 2) & 3) << 4;             // lane with quad=(l>>2)&3
        const float av   = __shfl(sc[l >> 4][l & 3], srcl);
        const int   idx  = __builtin_amdgcn_readlane(iv, l); // wave-uniform -> SGPR base
        oa[l & 3] = fmaf(av, (float)A16[(size_t)idx * DD + lane], oa[l & 3]);
    }
    out[(size_t)node * DD + lane] = ((oa[0] + oa[1]) + (oa[2] + oa[3])) * inv;
}

// ======================= FALLBACK (proven R6 path) ======================
#define FMR  112
#define FMT  7
#define FXSS 136

__global__ __launch_bounds__(256) void fb_prep_kernel(
    const float* __restrict__ W1, const float* __restrict__ W2,
    const float* __restrict__ w3, const float* __restrict__ b1,
    const float* __restrict__ b2,
    __bf16* __restrict__ wf, float* __restrict__ wsc)
{
    const int tid  = threadIdx.x;
    const int quad = tid >> 6;
    const int col  = tid & 63;
    __bf16* dst = wf + tid * 64;
    #pragma unroll
    for (int t = 0; t < 4; ++t)
        #pragma unroll
        for (int j = 0; j < 8; ++j) {
            int keff = t * 32 + quad * 8 + j;
            int krow = (keff < 64) ? keff : keff + 64;
            dst[t * 8 + j] = (__bf16)W1[krow * 64 + col];
        }
    #pragma unroll
    for (int t = 0; t < 2; ++t)
        #pragma unroll
        for (int j = 0; j < 8; ++j) {
            dst[32 + t * 8 + j] = (__bf16)W1[(64 + t * 32 + quad * 8 + j) * 64 + col];
            dst[48 + t * 8 + j] = (__bf16)W2[(t * 32 + quad * 8 + j) * 64 + col];
        }
    if (tid < 64) {
        wsc[tid] = w3[tid]; wsc[64 + tid] = b1[tid]; wsc[128 + tid] = b2[tid];
    }
}

__global__ __launch_bounds__(256, 5) void fb_agg_kernel(
    const int* __restrict__ nodes, const int* __restrict__ hva,
    const int* __restrict__ haf, const float* __restrict__ v2e,
    const float* __restrict__ a2e, const float* __restrict__ f2e,
    const __bf16* __restrict__ wf, const float* __restrict__ wsc,
    float* __restrict__ out)
{
    __shared__ __bf16 xs[FMR * FXSS];
    __shared__ float  pbuf[4 * FMR];
    const int tid = threadIdx.x;
    const int w = tid >> 6, lane = tid & 63, lq = lane & 15, quad = lane >> 4;
    const int col = w * 16 + lq;
    const int n0 = blockIdx.x * 2;
    {
        const int* hb = hva + n0 * HL;
        const int* fb = haf + n0 * HL;
        #pragma unroll
        for (int i = 0; i < 13; ++i) {
            int t = i * 256 + tid;
            if (t < 2 * HL * 2 * 16) {
                int r = t >> 4, q = t & 15;
                bool va = (r < 2 * HL);
                int gr = va ? r : r - 2 * HL;
                int idx = va ? hb[gr] : fb[gr];
                const float* src = (va ? a2e : f2e) + (size_t)idx * DD + q * 4;
                float4 v = *(const float4*)src;
                bf16x4 pk = {(__bf16)v.x, (__bf16)v.y, (__bf16)v.z, (__bf16)v.w};
                *(bf16x4*)&xs[gr * FXSS + (va ? 0 : DD) + q * 4] = pk;
            }
        }
    }
    bf16x8 repf[2];
    #pragma unroll
    for (int t = 0; t < 2; ++t)
        #pragma unroll
        for (int j = 0; j < 8; ++j) repf[t][j] = (__bf16)0.f;
    if (lq < 2) {
        int nd = nodes[n0 + lq];
        const float* rp = v2e + (size_t)nd * DD;
        #pragma unroll
        for (int t = 0; t < 2; ++t) {
            float4 v0 = *(const float4*)(rp + t * 32 + quad * 8);
            float4 v1 = *(const float4*)(rp + t * 32 + quad * 8 + 4);
            repf[t] = (bf16x8){(__bf16)v0.x, (__bf16)v0.y, (__bf16)v0.z, (__bf16)v0.w,
                               (__bf16)v1.x, (__bf16)v1.y, (__bf16)v1.z, (__bf16)v1.w};
        }
    }
    const __bf16* fbp = wf + (size_t)(quad * 64 + col) * 64;
    bf16x8 b1f[4], b1u[2], b2f[2];
    #pragma unroll
    for (int t = 0; t < 4; ++t) b1f[t] = *(const bf16x8*)(fbp + t * 8);
    #pragma unroll
    for (int t = 0; t < 2; ++t) {
        b1u[t] = *(const bf16x8*)(fbp + 32 + t * 8);
        b2f[t] = *(const bf16x8*)(fbp + 48 + t * 8);
    }
    const float w3c = wsc[col];
    const float b1c = wsc[64 + col];
    const float b2c = wsc[128 + col];
    f32x4 rb = {0.f, 0.f, 0.f, 0.f};
    #pragma unroll
    for (int t = 0; t < 2; ++t)
        rb = __builtin_amdgcn_mfma_f32_16x16x32_bf16(repf[t], b1u[t], rb, 0, 0, 0);
    const float bias0 = __shfl(rb[0], lq) + b1c;
    const float bias1 = __shfl(rb[1], lq) + b1c;
    __syncthreads();
    f32x4 acc[FMT];
    #pragma unroll
    for (int mt = 0; mt < FMT; ++mt)
        #pragma unroll
        for (int r = 0; r < 4; ++r) {
            int gr = mt * 16 + quad * 4 + r;
            acc[mt][r] = (gr >= HL) ? bias1 : bias0;
        }
    #pragma unroll
    for (int t = 0; t < 4; ++t)
        #pragma unroll
        for (int mt = 0; mt < FMT; ++mt) {
            bf16x8 a = *(const bf16x8*)&xs[(mt * 16 + lq) * FXSS + t * 32 + quad * 8];
            acc[mt] = __builtin_amdgcn_mfma_f32_16x16x32_bf16(a, b1f[t], acc[mt], 0, 0, 0);
        }
    __syncthreads();
    #pragma unroll
    for (int mt = 0; mt < FMT; ++mt)
        #pragma unroll
        for (int r = 0; r < 4; ++r) {
            int gr = mt * 16 + quad * 4 + r;
            xs[gr * FXSS + DD + col] = (__bf16)fmaxf(acc[mt][r], 0.f);
        }
    __syncthreads();
    f32x4 a2[FMT];
    #pragma unroll
    for (int mt = 0; mt < FMT; ++mt) a2[mt] = (f32x4){b2c, b2c, b2c, b2c};
    #pragma unroll
    for (int t = 0; t < 2; ++t)
        #pragma unroll
        for (int mt = 0; mt < FMT; ++mt) {
            bf16x8 a = *(const bf16x8*)&xs[(mt * 16 + lq) * FXSS + DD + t * 32 + quad * 8];
            a2[mt] = __builtin_amdgcn_mfma_f32_16x16x32_bf16(a, b2f[t], a2[mt], 0, 0, 0);
        }
    #pragma unroll
    for (int mt = 0; mt < FMT; ++mt) {
        float p0 = fmaxf(a2[mt][0], 0.f) * w3c;
        float p1 = fmaxf(a2[mt][1], 0.f) * w3c;
        float p2 = fmaxf(a2[mt][2], 0.f) * w3c;
        float p3 = fmaxf(a2[mt][3], 0.f) * w3c;
        #pragma unroll
        for (int m = 1; m < 16; m <<= 1) {
            p0 += __shfl_xor(p0, m); p1 += __shfl_xor(p1, m);
            p2 += __shfl_xor(p2, m); p3 += __shfl_xor(p3, m);
        }
        if (lq == 0) {
            int rowb = mt * 16 + quad * 4;
            pbuf[w * FMR + rowb + 0] = p0; pbuf[w * FMR + rowb + 1] = p1;
            pbuf[w * FMR + rowb + 2] = p2; pbuf[w * FMR + rowb + 3] = p3;
        }
    }
    __syncthreads();
    const int n = w & 1, lh = w >> 1;
    float att;
    {
        float s = -3.0e38f;
        if (lane < HL) {
            int gr = n * HL + lane;
            s = pbuf[gr] + pbuf[FMR + gr] + pbuf[2 * FMR + gr] + pbuf[3 * FMR + gr];
        }
        float mx = s;
        #pragma unroll
        for (int m = 1; m < 64; m <<= 1) mx = fmaxf(mx, __shfl_xor(mx, m));
        float e = (lane < HL) ? __expf(s - mx) : 0.f;
        float sm = e;
        #pragma unroll
        for (int m = 1; m < 64; m <<= 1) sm += __shfl_xor(sm, m);
        att = e / sm;
    }
    {
        float o = 0.f;
        const int lb = lh * 25;
        #pragma unroll
        for (int i = 0; i < 25; ++i) {
            int l = lb + i;
            float av = __shfl(att, l);
            o = fmaf(av, (float)xs[(n * HL + l) * FXSS + lane], o);
        }
        float* op = (float*)&xs[(100 + w) * FXSS + DD];
        op[lane] = o;
    }
    __syncthreads();
    if (w < 2) {
        const float* p0 = (const float*)&xs[(100 + w) * FXSS + DD];
        const float* p1 = (const float*)&xs[(100 + w + 2) * FXSS + DD];
        out[(size_t)(n0 + w) * DD + lane] = p0[lane] + p1[lane];
    }
}

// ================================ host ==================================
extern "C" void kernel_launch(void* const* d_in, const int* in_sizes, int n_in,
                              void* d_out, int out_size, void* d_ws, size_t ws_size,
                              hipStream_t stream) {
    const int*   nodes = (const int*)d_in[0];
    const int*   hva   = (const int*)d_in[1];
    const int*   haf   = (const int*)d_in[2];
    const float* v2e   = (const float*)d_in[3];
    const float* a2e   = (const float*)d_in[4];
    const float* f2e   = (const float*)d_in[5];
    const float* W1    = (const float*)d_in[6];
    const float* b1    = (const float*)d_in[7];
    const float* W2    = (const float*)d_in[8];
    const float* b2    = (const float*)d_in[9];
    const float* w3    = (const float*)d_in[10];
    // d_in[11] = b3: softmax shift-invariant — unused.
    float* out = (float*)d_out;

    const int N  = in_sizes[0];            // 8192
    const int nA = in_sizes[4] / DD;       // 100000
    const int nF = in_sizes[5] / DD;       // 100000

    size_t offA  = 0;                                     // nA x 64 f16
    size_t offF  = (offA + (size_t)nA * DD * 2 + 255) & ~(size_t)255;
    size_t offBA = (offF + (size_t)nF * DD * 2 + 255) & ~(size_t)255;
    size_t offWF = (offBA + (size_t)N * DD * 2 + 255) & ~(size_t)255;
    size_t offSC = offWF + 24 * 64 * 8 * 2;               // 24 frag combos
    size_t need  = offSC + 128 * 4;

    if (ws_size >= need) {
        _Float16* A16 = (_Float16*)((char*)d_ws + offA);
        _Float16* F16 = (_Float16*)((char*)d_ws + offF);
        _Float16* ba  = (_Float16*)((char*)d_ws + offBA);
        _Float16* wfr = (_Float16*)((char*)d_ws + offWF);
        float*    wsc = (float*)((char*)d_ws + offSC);

        const int GC = 2048;               // cvt-stream blocks
        const int GB = (N + 63) / 64;
        prep_all_kernel<<<GC + GB + 1, 256, 0, stream>>>(
            nodes, v2e, a2e, f2e, W1, b1, W2, b2, w3,
            A16, F16, ba, wfr, wsc, nA, nF, N, GC, GB);
        va_main_kernel<<<(N + 3) / 4, 256, 0, stream>>>(
            hva, haf, A16, F16, ba, wfr, wsc, out, N);
    } else {
        // workspace too small — proven R6 fallback (33 KB)
        __bf16* wf  = (__bf16*)d_ws;
        float*  wsc = (float*)((char*)d_ws + 256 * 64 * 2);
        fb_prep_kernel<<<1, 256, 0, stream>>>(W1, W2, w3, b1, b2, wf, wsc);
        fb_agg_kernel<<<N / 2, 256, 0, stream>>>(nodes, hva, haf, v2e, a2e, f2e,
                                                 wf, wsc, out);
    }
}

// Round 10
// 154.288 us; speedup vs baseline: 1.0447x; 1.0447x over previous
//
#include <hip/hip_runtime.h>
#include <hip/hip_bf16.h>

typedef __bf16    bf16x8 __attribute__((ext_vector_type(8)));
typedef __bf16    bf16x4 __attribute__((ext_vector_type(4)));
typedef _Float16  f16x8  __attribute__((ext_vector_type(8)));
typedef _Float16  f16x4  __attribute__((ext_vector_type(4)));
typedef float     f32x4  __attribute__((ext_vector_type(4)));

#define HL 50
#define DD 64

// ============================ ALGORITHM =================================
// R16: CONSOLIDATE ON R4 (best measured, 148us).  Fused-GEMM1 family
// (R12-R15) measured 43-64us main vs R4's ~27 — fusion's extra MFMA+LDS+
// register pressure on the latency-critical wave loses to split tables.
// Design: AE table merges A2=f16(a2e@W1[0:64]) and E=f16(a2e) per row
// (256B), F2 = f16(f2e@W1[128:192]), ba = f16(b1+rep@W1mid).  Main =
// wave-per-node gather + GEMM2 + in-reg softmax + AE e-half tail (L2-hot).
// R16 changes vs R4 (prep only): (a) cvt/E-write path widened to 8
// floats/lane (2x float4 load, 16B f16x8 stores) — halves staging insts,
// shrinks pipeline regs; (b) prep launch_bounds (256,5): cap 102 vs ~60
// live (safe), 5 blocks/CU on the stream.  Main byte-identical to R4.

// ---- fused prep: [0,GAF) A-tiles | [GAF,2GAF) F-tiles | bias | frags
__global__ __launch_bounds__(256, 5) void prep_all_kernel(
    const int*   __restrict__ nodes,
    const float* __restrict__ v2e,
    const float* __restrict__ a2e,
    const float* __restrict__ f2e,
    const float* __restrict__ W1,
    const float* __restrict__ b1,
    const float* __restrict__ W2,
    const float* __restrict__ b2,
    const float* __restrict__ w3,
    _Float16* __restrict__ AE, _Float16* __restrict__ F2,
    _Float16* __restrict__ ba16,
    _Float16* __restrict__ w2f, float* __restrict__ wsc,
    int nA, int nF, int N, int GAF, int GB)
{
    __shared__ __align__(16) _Float16 wlds[8 * 512];  // 8192 B: W1-part fragments
    __shared__ __align__(16) _Float16 es[64 * 72];    // 9216 B
    const int tid  = threadIdx.x;
    const int w    = tid >> 6, lane = tid & 63;
    const int lq   = lane & 15, quad = lane >> 4;
    const int bid  = blockIdx.x;

    if (bid < 2 * GAF) {
        // ==== embed transform: grid-stride tiles, DEPTH-2 pipeline ====
        const bool  isA    = (bid < GAF);
        const int   t0     = isA ? bid : bid - GAF;
        const int   nrows  = isA ? nA : nF;
        const int   NT     = (nrows + 63) >> 6;
        const int   dstride= isA ? 128 : 64;
        const float* src   = isA ? a2e : f2e;
        const float* Wp    = isA ? W1 : (W1 + 128 * DD);
        _Float16*   dst    = isA ? AE : F2;
        _Float16*   ws_    = &es[w * 16 * 72];         // wave-private slice

        // tile loader: 16 rows/wave, 8 floats/lane/iter (2 iters)
        auto loadtile = [&](int tb, float4 (&vv)[2][2], int (&gg)[2]) {
            const int r0w = tb * 64 + w * 16;
            #pragma unroll
            for (int i = 0; i < 2; ++i) {
                int t = i * 64 + lane;
                int row = t >> 3, seg = t & 7;
                int gr = r0w + row; if (gr >= nrows) gr = nrows - 1;
                gg[i] = gr;
                const float* p = src + (size_t)gr * DD + seg * 8;
                vv[i][0] = *(const float4*)p;
                vv[i][1] = *(const float4*)(p + 4);
            }
        };

        // process one tile; reissues its reg buffer with tile tbc+2*GAF
        auto proc = [&](int tbc, float4 (&vv)[2][2], int (&gg)[2]) {
            const int r0w = tbc * 64 + w * 16;
            // cvt -> wave-private LDS (+ free e_va half of AE for A), 16B wide
            #pragma unroll
            for (int i = 0; i < 2; ++i) {
                int t = i * 64 + lane;
                int row = t >> 3, seg = t & 7;
                float4 v0 = vv[i][0], v1 = vv[i][1];
                f16x8 pk = {(_Float16)v0.x, (_Float16)v0.y, (_Float16)v0.z, (_Float16)v0.w,
                            (_Float16)v1.x, (_Float16)v1.y, (_Float16)v1.z, (_Float16)v1.w};
                *(f16x8*)&ws_[row * 72 + seg * 8] = pk;
                if (isA)
                    *(f16x8*)(dst + (size_t)gg[i] * 128 + 64 + seg * 8) = pk;
            }
            // issue tile tbc+2*GAF into the just-freed buffer (2-iter lead)
            const int tn2 = tbc + 2 * GAF;
            if (tn2 < NT) loadtile(tn2, vv, gg);

            // fragments + 8 MFMA (4 col-tiles x 2 K-steps), wave-local
            f16x8 afr[2];
            #pragma unroll
            for (int t = 0; t < 2; ++t)
                afr[t] = *(const f16x8*)&ws_[lq * 72 + t * 32 + quad * 8];
            f32x4 acc[4];
            #pragma unroll
            for (int ct = 0; ct < 4; ++ct) {
                acc[ct] = (f32x4){0.f, 0.f, 0.f, 0.f};
                #pragma unroll
                for (int t = 0; t < 2; ++t) {
                    f16x8 bfr = *(const f16x8*)&wlds[(size_t)(ct * 2 + t) * 512 + lane * 8];
                    acc[ct] = __builtin_amdgcn_mfma_f32_16x16x32_f16(afr[t], bfr, acc[ct], 0, 0, 0);
                }
            }

            // repack via wave-private LDS, then vectorized global store
            #pragma unroll
            for (int ct = 0; ct < 4; ++ct)
                #pragma unroll
                for (int r = 0; r < 4; ++r)
                    ws_[(quad * 4 + r) * 72 + ct * 16 + lq] = (_Float16)acc[ct][r];
            {
                int row = lane >> 2, g = lane & 3;
                int gr  = r0w + row;
                if (gr < nrows) {
                    f16x8 v0 = *(const f16x8*)&ws_[row * 72 + g * 16];
                    f16x8 v1 = *(const f16x8*)&ws_[row * 72 + g * 16 + 8];
                    *(f16x8*)(dst + (size_t)gr * dstride + g * 16)     = v0;
                    *(f16x8*)(dst + (size_t)gr * dstride + g * 16 + 8) = v1;
                }
            }
        };

        // stage W1-part into LDS in fragment layout (L2-hot reads)
        #pragma unroll
        for (int h = 0; h < 2; ++h) {
            int combo = w + 4 * h;            // = ct*2 + t, combos 0..7
            int ct = combo >> 1, t = combo & 1;
            f16x8 pk;
            #pragma unroll
            for (int j = 0; j < 8; ++j)
                pk[j] = (_Float16)Wp[(t * 32 + quad * 8 + j) * DD + ct * 16 + lq];
            *(f16x8*)&wlds[(size_t)combo * 512 + lane * 8] = pk;
        }

        // prologue: two tiles' loads in flight across the barrier
        int    tb = t0;
        float4 vA[2][2], vB[2][2];
        int    gA[2], gB[2];
        loadtile(tb, vA, gA);
        if (tb + GAF < NT) loadtile(tb + GAF, vB, gB);

        __syncthreads();   // [only barrier] wlds ready; ws_ is wave-private

        for (;;) {
            proc(tb, vA, gA);                 // ping
            tb += GAF; if (tb >= NT) break;
            proc(tb, vB, gB);                 // pong
            tb += GAF; if (tb >= NT) break;
        }
    } else if (bid < 2 * GAF + GB) {
        // ---- bias branch: ba16[n][c] = f16(b1[c] + rep_n . W1[64:128, c]) ----
        const int col = w * 16 + lq;
        const int n0 = (bid - 2 * GAF) * 64;
        #pragma unroll
        for (int i = 0; i < 4; ++i) {
            int t = i * 256 + tid;
            int row = t >> 4, q = t & 15;
            int gn = n0 + row; if (gn >= N) gn = N - 1;
            int idx = nodes[gn];
            float4 v = *(const float4*)(v2e + (size_t)idx * DD + q * 4);
            f16x4 pk = {(_Float16)v.x, (_Float16)v.y, (_Float16)v.z, (_Float16)v.w};
            *(f16x4*)&es[row * 72 + q * 4] = pk;
        }
        f16x8 bfr[2];
        #pragma unroll
        for (int t = 0; t < 2; ++t)
            #pragma unroll
            for (int j = 0; j < 8; ++j)
                bfr[t][j] = (_Float16)W1[(64 + t * 32 + quad * 8 + j) * DD + col];
        const float b1c = b1[col];
        __syncthreads();

        f32x4 acc[4];
        #pragma unroll
        for (int mt = 0; mt < 4; ++mt) acc[mt] = (f32x4){0.f, 0.f, 0.f, 0.f};
        #pragma unroll
        for (int t = 0; t < 2; ++t)
            #pragma unroll
            for (int mt = 0; mt < 4; ++mt) {
                f16x8 a = *(const f16x8*)&es[(mt * 16 + lq) * 72 + t * 32 + quad * 8];
                acc[mt] = __builtin_amdgcn_mfma_f32_16x16x32_f16(a, bfr[t], acc[mt], 0, 0, 0);
            }
        #pragma unroll
        for (int mt = 0; mt < 4; ++mt)
            #pragma unroll
            for (int r = 0; r < 4; ++r) {
                int gn = n0 + mt * 16 + quad * 4 + r;
                if (gn < N) ba16[(size_t)gn * DD + col] = (_Float16)(acc[mt][r] + b1c);
            }
    } else {
        // ---- frag branch: W2 B-fragments (f16) + scalars ----
        const int ln = tid & 63, c0 = tid >> 6;
        #pragma unroll
        for (int h = 0; h < 2; ++h) {
            int combo = c0 + 4 * h;          // = ct*2 + t
            int ct = combo >> 1, t = combo & 1;
            _Float16* d = w2f + ((size_t)combo * 64 + ln) * 8;
            #pragma unroll
            for (int j = 0; j < 8; ++j)
                d[j] = (_Float16)W2[(t * 32 + (ln >> 4) * 8 + j) * DD + ct * 16 + (ln & 15)];
        }
        if (tid < 64) { wsc[tid] = w3[tid]; wsc[64 + tid] = b2[tid]; }
    }
}

// ---- main: ONE NODE PER WAVE — no barriers, no LDS, in-register softmax ----
__global__ __launch_bounds__(256, 4) void va_main_kernel(
    const int*      __restrict__ hva,
    const int*      __restrict__ haf,
    const _Float16* __restrict__ AE,
    const _Float16* __restrict__ F2,
    const _Float16* __restrict__ ba16,
    const _Float16* __restrict__ w2f,
    const float*    __restrict__ wsc,
    float*          __restrict__ out, int Ntot)
{
    const int tid  = threadIdx.x;
    const int w    = tid >> 6;
    const int lane = tid & 63;
    const int lq   = lane & 15;
    const int quad = lane >> 4;
    const int node = blockIdx.x * 4 + w;
    if (node >= Ntot) return;

    const int* hb = hva + node * HL;
    const int* fb = haf + node * HL;
    const int lclamp = (lane < HL) ? lane : 0;
    const int iv  = hb[lclamp];                 // lane l holds hva[l]
    const int ifv = fb[lclamp];                 // lane l holds haf[l]

    // ---- node-uniform bias fragments ----
    f16x8 bag[2];
    #pragma unroll
    for (int t = 0; t < 2; ++t)
        bag[t] = *(const f16x8*)(ba16 + (size_t)node * DD + t * 32 + quad * 8);

    // ---- gather A2/F2 fragments for all 4 row-tiles (burst issue) ----
    f16x8 a2g[4][2], f2g[4][2];
    #pragma unroll
    for (int mt = 0; mt < 4; ++mt) {
        const int row = mt * 16 + lq;
        const int ia  = __shfl(iv,  row);
        const int ifm = __shfl(ifv, row);
        const bool valid = (row < HL);          // compile-time true for mt<3
        #pragma unroll
        for (int t = 0; t < 2; ++t) {
            if (valid) {
                a2g[mt][t] = *(const f16x8*)(AE + (size_t)ia  * 128 + t * 32 + quad * 8);
                f2g[mt][t] = *(const f16x8*)(F2 + (size_t)ifm * DD  + t * 32 + quad * 8);
            }
        }
    }

    // ---- h1 = relu(A2 + F2 + ba), invalid rows forced to 0 ----
    f16x8 h1f[4][2];
    #pragma unroll
    for (int mt = 0; mt < 4; ++mt) {
        const bool valid = (mt * 16 + lq) < HL;
        #pragma unroll
        for (int t = 0; t < 2; ++t) {
            f16x8 h = a2g[mt][t] + f2g[mt][t] + bag[t];
            #pragma unroll
            for (int j = 0; j < 8; ++j)
                h1f[mt][t][j] = (valid && h[j] > (_Float16)0.f) ? h[j] : (_Float16)0.f;
        }
    }

    // ---- GEMM2 (4 row-tiles x 4 col-tiles x 2 K) + score partials ----
    float sc[4][4];
    #pragma unroll
    for (int mt = 0; mt < 4; ++mt)
        #pragma unroll
        for (int r = 0; r < 4; ++r) sc[mt][r] = 0.f;

    #pragma unroll
    for (int ct = 0; ct < 4; ++ct) {
        const float b2c = wsc[64 + ct * 16 + lq];
        const float w3c = wsc[ct * 16 + lq];
        f16x8 bfr[2];
        #pragma unroll
        for (int t = 0; t < 2; ++t)
            bfr[t] = *(const f16x8*)(w2f + ((size_t)(ct * 2 + t) * 64 + lane) * 8);
        #pragma unroll
        for (int mt = 0; mt < 4; ++mt) {
            f32x4 acc = {b2c, b2c, b2c, b2c};
            #pragma unroll
            for (int t = 0; t < 2; ++t)
                acc = __builtin_amdgcn_mfma_f32_16x16x32_f16(h1f[mt][t], bfr[t], acc, 0, 0, 0);
            #pragma unroll
            for (int r = 0; r < 4; ++r)
                sc[mt][r] = fmaf(fmaxf(acc[r], 0.f), w3c, sc[mt][r]);
        }
    }

    // ---- reduce scores over lq (each lane then holds its quad's 16 rows) ----
    #pragma unroll
    for (int mt = 0; mt < 4; ++mt)
        #pragma unroll
        for (int r = 0; r < 4; ++r)
            #pragma unroll
            for (int m = 1; m < 16; m <<= 1)
                sc[mt][r] += __shfl_xor(sc[mt][r], m);

    // ---- in-register softmax over 50 rows (row = mt*16 + quad*4 + r) ----
    #pragma unroll
    for (int r = 0; r < 4; ++r)
        if (48 + quad * 4 + r >= HL) sc[3][r] = -3.0e38f;   // rows 50..63

    float mx = sc[0][0];
    #pragma unroll
    for (int mt = 0; mt < 4; ++mt)
        #pragma unroll
        for (int r = 0; r < 4; ++r) mx = fmaxf(mx, sc[mt][r]);
    mx = fmaxf(mx, __shfl_xor(mx, 16));
    mx = fmaxf(mx, __shfl_xor(mx, 32));

    float sm = 0.f;
    #pragma unroll
    for (int mt = 0; mt < 4; ++mt)
        #pragma unroll
        for (int r = 0; r < 4; ++r) {
            sc[mt][r] = __expf(sc[mt][r] - mx);             // 0 for invalid rows
            sm += sc[mt][r];
        }
    sm += __shfl_xor(sm, 16);
    sm += __shfl_xor(sm, 32);
    const float inv = 1.f / sm;

    // ---- weighted e_va sum: AE e_va half is L2-hot from the A2 fetch ----
    float oa[4] = {0.f, 0.f, 0.f, 0.f};
    #pragma unroll
    for (int l = 0; l < HL; ++l) {
        const int   srcl = ((l >> 2) & 3) << 4;             // lane with quad=(l>>2)&3
        const float av   = __shfl(sc[l >> 4][l & 3], srcl);
        const int   idx  = __builtin_amdgcn_readlane(iv, l); // wave-uniform -> SGPR base
        oa[l & 3] = fmaf(av, (float)AE[(size_t)idx * 128 + 64 + lane], oa[l & 3]);
    }
    out[(size_t)node * DD + lane] = ((oa[0] + oa[1]) + (oa[2] + oa[3])) * inv;
}

// ======================= FALLBACK (proven R6 path) ======================
#define FMR  112
#define FMT  7
#define FXSS 136

__global__ __launch_bounds__(256) void fb_prep_kernel(
    const float* __restrict__ W1, const float* __restrict__ W2,
    const float* __restrict__ w3, const float* __restrict__ b1,
    const float* __restrict__ b2,
    __bf16* __restrict__ wf, float* __restrict__ wsc)
{
    const int tid  = threadIdx.x;
    const int quad = tid >> 6;
    const int col  = tid & 63;
    __bf16* dst = wf + tid * 64;
    #pragma unroll
    for (int t = 0; t < 4; ++t)
        #pragma unroll
        for (int j = 0; j < 8; ++j) {
            int keff = t * 32 + quad * 8 + j;
            int krow = (keff < 64) ? keff : keff + 64;
            dst[t * 8 + j] = (__bf16)W1[krow * 64 + col];
        }
    #pragma unroll
    for (int t = 0; t < 2; ++t)
        #pragma unroll
        for (int j = 0; j < 8; ++j) {
            dst[32 + t * 8 + j] = (__bf16)W1[(64 + t * 32 + quad * 8 + j) * 64 + col];
            dst[48 + t * 8 + j] = (__bf16)W2[(t * 32 + quad * 8 + j) * 64 + col];
        }
    if (tid < 64) {
        wsc[tid] = w3[tid]; wsc[64 + tid] = b1[tid]; wsc[128 + tid] = b2[tid];
    }
}

__global__ __launch_bounds__(256, 5) void fb_agg_kernel(
    const int* __restrict__ nodes, const int* __restrict__ hva,
    const int* __restrict__ haf, const float* __restrict__ v2e,
    const float* __restrict__ a2e, const float* __restrict__ f2e,
    const __bf16* __restrict__ wf, const float* __restrict__ wsc,
    float* __restrict__ out)
{
    __shared__ __bf16 xs[FMR * FXSS];
    __shared__ float  pbuf[4 * FMR];
    const int tid = threadIdx.x;
    const int w = tid >> 6, lane = tid & 63, lq = lane & 15, quad = lane >> 4;
    const int col = w * 16 + lq;
    const int n0 = blockIdx.x * 2;
    {
        const int* hb = hva + n0 * HL;
        const int* fb = haf + n0 * HL;
        #pragma unroll
        for (int i = 0; i < 13; ++i) {
            int t = i * 256 + tid;
            if (t < 2 * HL * 2 * 16) {
                int r = t >> 4, q = t & 15;
                bool va = (r < 2 * HL);
                int gr = va ? r : r - 2 * HL;
                int idx = va ? hb[gr] : fb[gr];
                const float* src = (va ? a2e : f2e) + (size_t)idx * DD + q * 4;
                float4 v = *(const float4*)src;
                bf16x4 pk = {(__bf16)v.x, (__bf16)v.y, (__bf16)v.z, (__bf16)v.w};
                *(bf16x4*)&xs[gr * FXSS + (va ? 0 : DD) + q * 4] = pk;
            }
        }
    }
    bf16x8 repf[2];
    #pragma unroll
    for (int t = 0; t < 2; ++t)
        #pragma unroll
        for (int j = 0; j < 8; ++j) repf[t][j] = (__bf16)0.f;
    if (lq < 2) {
        int nd = nodes[n0 + lq];
        const float* rp = v2e + (size_t)nd * DD;
        #pragma unroll
        for (int t = 0; t < 2; ++t) {
            float4 v0 = *(const float4*)(rp + t * 32 + quad * 8);
            float4 v1 = *(const float4*)(rp + t * 32 + quad * 8 + 4);
            repf[t] = (bf16x8){(__bf16)v0.x, (__bf16)v0.y, (__bf16)v0.z, (__bf16)v0.w,
                               (__bf16)v1.x, (__bf16)v1.y, (__bf16)v1.z, (__bf16)v1.w};
        }
    }
    const __bf16* fbp = wf + (size_t)(quad * 64 + col) * 64;
    bf16x8 b1f[4], b1u[2], b2f[2];
    #pragma unroll
    for (int t = 0; t < 4; ++t) b1f[t] = *(const bf16x8*)(fbp + t * 8);
    #pragma unroll
    for (int t = 0; t < 2; ++t) {
        b1u[t] = *(const bf16x8*)(fbp + 32 + t * 8);
        b2f[t] = *(const bf16x8*)(fbp + 48 + t * 8);
    }
    const float w3c = wsc[col];
    const float b1c = wsc[64 + col];
    const float b2c = wsc[128 + col];
    f32x4 rb = {0.f, 0.f, 0.f, 0.f};
    #pragma unroll
    for (int t = 0; t < 2; ++t)
        rb = __builtin_amdgcn_mfma_f32_16x16x32_bf16(repf[t], b1u[t], rb, 0, 0, 0);
    const float bias0 = __shfl(rb[0], lq) + b1c;
    const float bias1 = __shfl(rb[1], lq) + b1c;
    __syncthreads();
    f32x4 acc[FMT];
    #pragma unroll
    for (int mt = 0; mt < FMT; ++mt)
        #pragma unroll
        for (int r = 0; r < 4; ++r) {
            int gr = mt * 16 + quad * 4 + r;
            acc[mt][r] = (gr >= HL) ? bias1 : bias0;
        }
    #pragma unroll
    for (int t = 0; t < 4; ++t)
        #pragma unroll
        for (int mt = 0; mt < FMT; ++mt) {
            bf16x8 a = *(const bf16x8*)&xs[(mt * 16 + lq) * FXSS + t * 32 + quad * 8];
            acc[mt] = __builtin_amdgcn_mfma_f32_16x16x32_bf16(a, b1f[t], acc[mt], 0, 0, 0);
        }
    __syncthreads();
    #pragma unroll
    for (int mt = 0; mt < FMT; ++mt)
        #pragma unroll
        for (int r = 0; r < 4; ++r) {
            int gr = mt * 16 + quad * 4 + r;
            xs[gr * FXSS + DD + col] = (__bf16)fmaxf(acc[mt][r], 0.f);
        }
    __syncthreads();
    f32x4 a2[FMT];
    #pragma unroll
    for (int mt = 0; mt < FMT; ++mt) a2[mt] = (f32x4){b2c, b2c, b2c, b2c};
    #pragma unroll
    for (int t = 0; t < 2; ++t)
        #pragma unroll
        for (int mt = 0; mt < FMT; ++mt) {
            bf16x8 a = *(const bf16x8*)&xs[(mt * 16 + lq) * FXSS + DD + t * 32 + quad * 8];
            a2[mt] = __builtin_amdgcn_mfma_f32_16x16x32_bf16(a, b2f[t], a2[mt], 0, 0, 0);
        }
    #pragma unroll
    for (int mt = 0; mt < FMT; ++mt) {
        float p0 = fmaxf(a2[mt][0], 0.f) * w3c;
        float p1 = fmaxf(a2[mt][1], 0.f) * w3c;
        float p2 = fmaxf(a2[mt][2], 0.f) * w3c;
        float p3 = fmaxf(a2[mt][3], 0.f) * w3c;
        #pragma unroll
        for (int m = 1; m < 16; m <<= 1) {
            p0 += __shfl_xor(p0, m); p1 += __shfl_xor(p1, m);
            p2 += __shfl_xor(p2, m); p3 += __shfl_xor(p3, m);
        }
        if (lq == 0) {
            int rowb = mt * 16 + quad * 4;
            pbuf[w * FMR + rowb + 0] = p0; pbuf[w * FMR + rowb + 1] = p1;
            pbuf[w * FMR + rowb + 2] = p2; pbuf[w * FMR + rowb + 3] = p3;
        }
    }
    __syncthreads();
    const int n = w & 1, lh = w >> 1;
    float att;
    {
        float s = -3.0e38f;
        if (lane < HL) {
            int gr = n * HL + lane;
            s = pbuf[gr] + pbuf[FMR + gr] + pbuf[2 * FMR + gr] + pbuf[3 * FMR + gr];
        }
        float mx = s;
        #pragma unroll
        for (int m = 1; m < 64; m <<= 1) mx = fmaxf(mx, __shfl_xor(mx, m));
        float e = (lane < HL) ? __expf(s - mx) : 0.f;
        float sm = e;
        #pragma unroll
        for (int m = 1; m < 64; m <<= 1) sm += __shfl_xor(sm, m);
        att = e / sm;
    }
    {
        float o = 0.f;
        const int lb = lh * 25;
        #pragma unroll
        for (int i = 0; i < 25; ++i) {
            int l = lb + i;
            float av = __shfl(att, l);
            o = fmaf(av, (float)xs[(n * HL + l) * FXSS + lane], o);
        }
        float* op = (float*)&xs[(100 + w) * FXSS + DD];
        op[lane] = o;
    }
    __syncthreads();
    if (w < 2) {
        const float* p0 = (const float*)&xs[(100 + w) * FXSS + DD];
        const float* p1 = (const float*)&xs[(100 + w + 2) * FXSS + DD];
        out[(size_t)(n0 + w) * DD + lane] = p0[lane] + p1[lane];
    }
}

// ================================ host ==================================
extern "C" void kernel_launch(void* const* d_in, const int* in_sizes, int n_in,
                              void* d_out, int out_size, void* d_ws, size_t ws_size,
                              hipStream_t stream) {
    const int*   nodes = (const int*)d_in[0];
    const int*   hva   = (const int*)d_in[1];
    const int*   haf   = (const int*)d_in[2];
    const float* v2e   = (const float*)d_in[3];
    const float* a2e   = (const float*)d_in[4];
    const float* f2e   = (const float*)d_in[5];
    const float* W1    = (const float*)d_in[6];
    const float* b1    = (const float*)d_in[7];
    const float* W2    = (const float*)d_in[8];
    const float* b2    = (const float*)d_in[9];
    const float* w3    = (const float*)d_in[10];
    // d_in[11] = b3: softmax shift-invariant — unused.
    float* out = (float*)d_out;

    const int N  = in_sizes[0];            // 8192
    const int nA = in_sizes[4] / DD;       // 100000
    const int nF = in_sizes[5] / DD;       // 100000

    size_t offAE = 0;                                     // nA x 128 f16
    size_t offF2 = (offAE + (size_t)nA * 128 * 2 + 255) & ~(size_t)255;
    size_t offBA = (offF2 + (size_t)nF * DD * 2 + 255) & ~(size_t)255;
    size_t offWF = (offBA + (size_t)N * DD * 2 + 255) & ~(size_t)255;
    size_t offSC = offWF + 8 * 64 * 8 * 2;
    size_t need  = offSC + 128 * 4;

    if (ws_size >= need) {
        _Float16* AE  = (_Float16*)((char*)d_ws + offAE);
        _Float16* F2  = (_Float16*)((char*)d_ws + offF2);
        _Float16* ba  = (_Float16*)((char*)d_ws + offBA);
        _Float16* w2f = (_Float16*)((char*)d_ws + offWF);
        float*    wsc = (float*)((char*)d_ws + offSC);

        const int GAF = 320;               // grid-stride blocks per table
        const int GB  = (N + 63) / 64;
        prep_all_kernel<<<2 * GAF + GB + 1, 256, 0, stream>>>(
            nodes, v2e, a2e, f2e, W1, b1, W2, b2, w3,
            AE, F2, ba, w2f, wsc, nA, nF, N, GAF, GB);
        va_main_kernel<<<(N + 3) / 4, 256, 0, stream>>>(
            hva, haf, AE, F2, ba, w2f, wsc, out, N);
    } else {
        // workspace too small for precompute path — proven R6 fallback (33 KB)
        __bf16* wf  = (__bf16*)d_ws;
        float*  wsc = (float*)((char*)d_ws + 256 * 64 * 2);
        fb_prep_kernel<<<1, 256, 0, stream>>>(W1, W2, w3, b1, b2, wf, wsc);
        fb_agg_kernel<<<N / 2, 256, 0, stream>>>(nodes, hva, haf, v2e, a2e, f2e,
                                                 wf, wsc, out);
    }
}

// Round 11
// 153.491 us; speedup vs baseline: 1.0501x; 1.0052x over previous
//
#include <hip/hip_runtime.h>
#include <hip/hip_bf16.h>

typedef __bf16    bf16x8 __attribute__((ext_vector_type(8)));
typedef __bf16    bf16x4 __attribute__((ext_vector_type(4)));
typedef _Float16  f16x8  __attribute__((ext_vector_type(8)));
typedef _Float16  f16x4  __attribute__((ext_vector_type(4)));
typedef float     f32x4  __attribute__((ext_vector_type(4)));

#define HL 50
#define DD 64

// ============================ ALGORITHM =================================
// R17: R4/R16 split design; prep A/F branch rewritten with SWAPPED MFMA
// OPERANDS: D[out_ch][row] = W1part^T @ x^T.
//  - A-frag(W1^T) staging == old B-frag staging (wlds unchanged).
//  - B-frag(x^T) = x[row=lq][t*32+quad*8..+8] -> loaded DIRECTLY from
//    global in fragment layout (no LDS x-stage).
//  - C-layout: col=lq=table_row, M=ct*16+quad*4+r=out_ch -> each lane
//    stores f16x4 (4 consecutive cols of its row) straight to the table
//    (no repack LDS).  A/F branch now has ZERO x-side LDS traffic.
// Tables: AE row = [A2 half | e_va half] (256B), F2 (128B), ba, w2f —
// main kernel byte-identical to R4 (proven ~27us).

// ---- fused prep: [0,GAF) A-tiles | [GAF,2GAF) F-tiles | bias | frags
__global__ __launch_bounds__(256, 4) void prep_all_kernel(
    const int*   __restrict__ nodes,
    const float* __restrict__ v2e,
    const float* __restrict__ a2e,
    const float* __restrict__ f2e,
    const float* __restrict__ W1,
    const float* __restrict__ b1,
    const float* __restrict__ W2,
    const float* __restrict__ b2,
    const float* __restrict__ w3,
    _Float16* __restrict__ AE, _Float16* __restrict__ F2,
    _Float16* __restrict__ ba16,
    _Float16* __restrict__ w2f, float* __restrict__ wsc,
    int nA, int nF, int N, int GAF, int GB)
{
    __shared__ __align__(16) _Float16 wlds[8 * 512];  // 8192 B: W1-part A-frags
    __shared__ __align__(16) _Float16 es[64 * 72];    // 9216 B (bias branch)
    const int tid  = threadIdx.x;
    const int w    = tid >> 6, lane = tid & 63;
    const int lq   = lane & 15, quad = lane >> 4;
    const int bid  = blockIdx.x;

    if (bid < 2 * GAF) {
        // ==== embed transform: swapped-operand GEMM, no x-side LDS ====
        const bool  isA    = (bid < GAF);
        const int   t0     = isA ? bid : bid - GAF;
        const int   nrows  = isA ? nA : nF;
        const int   NT     = (nrows + 63) >> 6;
        const int   dstride= isA ? 128 : 64;
        const float* src   = isA ? a2e : f2e;
        const float* Wp    = isA ? W1 : (W1 + 128 * DD);
        _Float16*   dst    = isA ? AE : F2;

        // loader: lane owns table row (tile*64 + w*16 + lq), reads its
        // B-frag chunks cols t*32+quad*8..+8 (4 quads -> 128B/row contig)
        auto loadtile = [&](int tb, float4 (&vv)[2][2], int &gg) {
            int gr = tb * 64 + w * 16 + lq;
            if (gr >= nrows) gr = nrows - 1;
            gg = gr;
            #pragma unroll
            for (int t = 0; t < 2; ++t) {
                const float* p = src + (size_t)gr * DD + t * 32 + quad * 8;
                vv[t][0] = *(const float4*)p;
                vv[t][1] = *(const float4*)(p + 4);
            }
        };

        // process one tile; reissues its reg buffer with tile tbc+2*GAF
        auto proc = [&](int tbc, float4 (&vv)[2][2], int &gg) {
            const int grow = gg;
            // cvt to B-frags (+ free e_va half of AE for A)
            f16x8 xb[2];
            #pragma unroll
            for (int t = 0; t < 2; ++t) {
                float4 v0 = vv[t][0], v1 = vv[t][1];
                xb[t] = (f16x8){(_Float16)v0.x, (_Float16)v0.y, (_Float16)v0.z, (_Float16)v0.w,
                                (_Float16)v1.x, (_Float16)v1.y, (_Float16)v1.z, (_Float16)v1.w};
                if (isA)
                    *(f16x8*)(dst + (size_t)grow * 128 + 64 + t * 32 + quad * 8) = xb[t];
            }
            // issue tile tbc+2*GAF into the just-freed buffer (2-iter lead)
            const int tn2 = tbc + 2 * GAF;
            if (tn2 < NT) loadtile(tn2, vv, gg);

            // 8 MFMA: acc[ct] = W1part^T (A, from wlds) @ x^T (B, xb)
            f32x4 acc[4];
            #pragma unroll
            for (int ct = 0; ct < 4; ++ct) {
                acc[ct] = (f32x4){0.f, 0.f, 0.f, 0.f};
                #pragma unroll
                for (int t = 0; t < 2; ++t) {
                    f16x8 wfr = *(const f16x8*)&wlds[(size_t)(ct * 2 + t) * 512 + lane * 8];
                    acc[ct] = __builtin_amdgcn_mfma_f32_16x16x32_f16(wfr, xb[t], acc[ct], 0, 0, 0);
                }
            }

            // direct store: lane holds out_chs ct*16+quad*4..+4 of row grow
            #pragma unroll
            for (int ct = 0; ct < 4; ++ct) {
                f16x4 pk = {(_Float16)acc[ct][0], (_Float16)acc[ct][1],
                            (_Float16)acc[ct][2], (_Float16)acc[ct][3]};
                *(f16x4*)(dst + (size_t)grow * dstride + ct * 16 + quad * 4) = pk;
            }
        };

        // stage W1-part A-fragments into LDS (same layout as old B-frags)
        #pragma unroll
        for (int h = 0; h < 2; ++h) {
            int combo = w + 4 * h;            // = ct*2 + t, combos 0..7
            int ct = combo >> 1, t = combo & 1;
            f16x8 pk;
            #pragma unroll
            for (int j = 0; j < 8; ++j)
                pk[j] = (_Float16)Wp[(t * 32 + quad * 8 + j) * DD + ct * 16 + lq];
            *(f16x8*)&wlds[(size_t)combo * 512 + lane * 8] = pk;
        }

        // prologue: two tiles' loads in flight across the barrier
        int    tb = t0;
        float4 vA[2][2], vB[2][2];
        int    gA = 0, gB = 0;
        loadtile(tb, vA, gA);
        if (tb + GAF < NT) loadtile(tb + GAF, vB, gB);

        __syncthreads();   // [only barrier] wlds ready

        for (;;) {
            proc(tb, vA, gA);                 // ping
            tb += GAF; if (tb >= NT) break;
            proc(tb, vB, gB);                 // pong
            tb += GAF; if (tb >= NT) break;
        }
    } else if (bid < 2 * GAF + GB) {
        // ---- bias branch: ba16[n][c] = f16(b1[c] + rep_n . W1[64:128, c]) ----
        const int col = w * 16 + lq;
        const int n0 = (bid - 2 * GAF) * 64;
        #pragma unroll
        for (int i = 0; i < 4; ++i) {
            int t = i * 256 + tid;
            int row = t >> 4, q = t & 15;
            int gn = n0 + row; if (gn >= N) gn = N - 1;
            int idx = nodes[gn];
            float4 v = *(const float4*)(v2e + (size_t)idx * DD + q * 4);
            f16x4 pk = {(_Float16)v.x, (_Float16)v.y, (_Float16)v.z, (_Float16)v.w};
            *(f16x4*)&es[row * 72 + q * 4] = pk;
        }
        f16x8 bfr[2];
        #pragma unroll
        for (int t = 0; t < 2; ++t)
            #pragma unroll
            for (int j = 0; j < 8; ++j)
                bfr[t][j] = (_Float16)W1[(64 + t * 32 + quad * 8 + j) * DD + col];
        const float b1c = b1[col];
        __syncthreads();

        f32x4 acc[4];
        #pragma unroll
        for (int mt = 0; mt < 4; ++mt) acc[mt] = (f32x4){0.f, 0.f, 0.f, 0.f};
        #pragma unroll
        for (int t = 0; t < 2; ++t)
            #pragma unroll
            for (int mt = 0; mt < 4; ++mt) {
                f16x8 a = *(const f16x8*)&es[(mt * 16 + lq) * 72 + t * 32 + quad * 8];
                acc[mt] = __builtin_amdgcn_mfma_f32_16x16x32_f16(a, bfr[t], acc[mt], 0, 0, 0);
            }
        #pragma unroll
        for (int mt = 0; mt < 4; ++mt)
            #pragma unroll
            for (int r = 0; r < 4; ++r) {
                int gn = n0 + mt * 16 + quad * 4 + r;
                if (gn < N) ba16[(size_t)gn * DD + col] = (_Float16)(acc[mt][r] + b1c);
            }
    } else {
        // ---- frag branch: W2 B-fragments (f16) + scalars ----
        const int ln = tid & 63, c0 = tid >> 6;
        #pragma unroll
        for (int h = 0; h < 2; ++h) {
            int combo = c0 + 4 * h;          // = ct*2 + t
            int ct = combo >> 1, t = combo & 1;
            _Float16* d = w2f + ((size_t)combo * 64 + ln) * 8;
            #pragma unroll
            for (int j = 0; j < 8; ++j)
                d[j] = (_Float16)W2[(t * 32 + (ln >> 4) * 8 + j) * DD + ct * 16 + (ln & 15)];
        }
        if (tid < 64) { wsc[tid] = w3[tid]; wsc[64 + tid] = b2[tid]; }
    }
}

// ---- main: ONE NODE PER WAVE — no barriers, no LDS, in-register softmax ----
__global__ __launch_bounds__(256, 4) void va_main_kernel(
    const int*      __restrict__ hva,
    const int*      __restrict__ haf,
    const _Float16* __restrict__ AE,
    const _Float16* __restrict__ F2,
    const _Float16* __restrict__ ba16,
    const _Float16* __restrict__ w2f,
    const float*    __restrict__ wsc,
    float*          __restrict__ out, int Ntot)
{
    const int tid  = threadIdx.x;
    const int w    = tid >> 6;
    const int lane = tid & 63;
    const int lq   = lane & 15;
    const int quad = lane >> 4;
    const int node = blockIdx.x * 4 + w;
    if (node >= Ntot) return;

    const int* hb = hva + node * HL;
    const int* fb = haf + node * HL;
    const int lclamp = (lane < HL) ? lane : 0;
    const int iv  = hb[lclamp];                 // lane l holds hva[l]
    const int ifv = fb[lclamp];                 // lane l holds haf[l]

    // ---- node-uniform bias fragments ----
    f16x8 bag[2];
    #pragma unroll
    for (int t = 0; t < 2; ++t)
        bag[t] = *(const f16x8*)(ba16 + (size_t)node * DD + t * 32 + quad * 8);

    // ---- gather A2/F2 fragments for all 4 row-tiles (burst issue) ----
    f16x8 a2g[4][2], f2g[4][2];
    #pragma unroll
    for (int mt = 0; mt < 4; ++mt) {
        const int row = mt * 16 + lq;
        const int ia  = __shfl(iv,  row);
        const int ifm = __shfl(ifv, row);
        const bool valid = (row < HL);          // compile-time true for mt<3
        #pragma unroll
        for (int t = 0; t < 2; ++t) {
            if (valid) {
                a2g[mt][t] = *(const f16x8*)(AE + (size_t)ia  * 128 + t * 32 + quad * 8);
                f2g[mt][t] = *(const f16x8*)(F2 + (size_t)ifm * DD  + t * 32 + quad * 8);
            }
        }
    }

    // ---- h1 = relu(A2 + F2 + ba), invalid rows forced to 0 ----
    f16x8 h1f[4][2];
    #pragma unroll
    for (int mt = 0; mt < 4; ++mt) {
        const bool valid = (mt * 16 + lq) < HL;
        #pragma unroll
        for (int t = 0; t < 2; ++t) {
            f16x8 h = a2g[mt][t] + f2g[mt][t] + bag[t];
            #pragma unroll
            for (int j = 0; j < 8; ++j)
                h1f[mt][t][j] = (valid && h[j] > (_Float16)0.f) ? h[j] : (_Float16)0.f;
        }
    }

    // ---- GEMM2 (4 row-tiles x 4 col-tiles x 2 K) + score partials ----
    float sc[4][4];
    #pragma unroll
    for (int mt = 0; mt < 4; ++mt)
        #pragma unroll
        for (int r = 0; r < 4; ++r) sc[mt][r] = 0.f;

    #pragma unroll
    for (int ct = 0; ct < 4; ++ct) {
        const float b2c = wsc[64 + ct * 16 + lq];
        const float w3c = wsc[ct * 16 + lq];
        f16x8 bfr[2];
        #pragma unroll
        for (int t = 0; t < 2; ++t)
            bfr[t] = *(const f16x8*)(w2f + ((size_t)(ct * 2 + t) * 64 + lane) * 8);
        #pragma unroll
        for (int mt = 0; mt < 4; ++mt) {
            f32x4 acc = {b2c, b2c, b2c, b2c};
            #pragma unroll
            for (int t = 0; t < 2; ++t)
                acc = __builtin_amdgcn_mfma_f32_16x16x32_f16(h1f[mt][t], bfr[t], acc, 0, 0, 0);
            #pragma unroll
            for (int r = 0; r < 4; ++r)
                sc[mt][r] = fmaf(fmaxf(acc[r], 0.f), w3c, sc[mt][r]);
        }
    }

    // ---- reduce scores over lq (each lane then holds its quad's 16 rows) ----
    #pragma unroll
    for (int mt = 0; mt < 4; ++mt)
        #pragma unroll
        for (int r = 0; r < 4; ++r)
            #pragma unroll
            for (int m = 1; m < 16; m <<= 1)
                sc[mt][r] += __shfl_xor(sc[mt][r], m);

    // ---- in-register softmax over 50 rows (row = mt*16 + quad*4 + r) ----
    #pragma unroll
    for (int r = 0; r < 4; ++r)
        if (48 + quad * 4 + r >= HL) sc[3][r] = -3.0e38f;   // rows 50..63

    float mx = sc[0][0];
    #pragma unroll
    for (int mt = 0; mt < 4; ++mt)
        #pragma unroll
        for (int r = 0; r < 4; ++r) mx = fmaxf(mx, sc[mt][r]);
    mx = fmaxf(mx, __shfl_xor(mx, 16));
    mx = fmaxf(mx, __shfl_xor(mx, 32));

    float sm = 0.f;
    #pragma unroll
    for (int mt = 0; mt < 4; ++mt)
        #pragma unroll
        for (int r = 0; r < 4; ++r) {
            sc[mt][r] = __expf(sc[mt][r] - mx);             // 0 for invalid rows
            sm += sc[mt][r];
        }
    sm += __shfl_xor(sm, 16);
    sm += __shfl_xor(sm, 32);
    const float inv = 1.f / sm;

    // ---- weighted e_va sum: AE e_va half is L2-hot from the A2 fetch ----
    float oa[4] = {0.f, 0.f, 0.f, 0.f};
    #pragma unroll
    for (int l = 0; l < HL; ++l) {
        const int   srcl = ((l >> 2) & 3) << 4;             // lane with quad=(l>>2)&3
        const float av   = __shfl(sc[l >> 4][l & 3], srcl);
        const int   idx  = __builtin_amdgcn_readlane(iv, l); // wave-uniform -> SGPR base
        oa[l & 3] = fmaf(av, (float)AE[(size_t)idx * 128 + 64 + lane], oa[l & 3]);
    }
    out[(size_t)node * DD + lane] = ((oa[0] + oa[1]) + (oa[2] + oa[3])) * inv;
}

// ======================= FALLBACK (proven R6 path) ======================
#define FMR  112
#define FMT  7
#define FXSS 136

__global__ __launch_bounds__(256) void fb_prep_kernel(
    const float* __restrict__ W1, const float* __restrict__ W2,
    const float* __restrict__ w3, const float* __restrict__ b1,
    const float* __restrict__ b2,
    __bf16* __restrict__ wf, float* __restrict__ wsc)
{
    const int tid  = threadIdx.x;
    const int quad = tid >> 6;
    const int col  = tid & 63;
    __bf16* dst = wf + tid * 64;
    #pragma unroll
    for (int t = 0; t < 4; ++t)
        #pragma unroll
        for (int j = 0; j < 8; ++j) {
            int keff = t * 32 + quad * 8 + j;
            int krow = (keff < 64) ? keff : keff + 64;
            dst[t * 8 + j] = (__bf16)W1[krow * 64 + col];
        }
    #pragma unroll
    for (int t = 0; t < 2; ++t)
        #pragma unroll
        for (int j = 0; j < 8; ++j) {
            dst[32 + t * 8 + j] = (__bf16)W1[(64 + t * 32 + quad * 8 + j) * 64 + col];
            dst[48 + t * 8 + j] = (__bf16)W2[(t * 32 + quad * 8 + j) * 64 + col];
        }
    if (tid < 64) {
        wsc[tid] = w3[tid]; wsc[64 + tid] = b1[tid]; wsc[128 + tid] = b2[tid];
    }
}

__global__ __launch_bounds__(256, 5) void fb_agg_kernel(
    const int* __restrict__ nodes, const int* __restrict__ hva,
    const int* __restrict__ haf, const float* __restrict__ v2e,
    const float* __restrict__ a2e, const float* __restrict__ f2e,
    const __bf16* __restrict__ wf, const float* __restrict__ wsc,
    float* __restrict__ out)
{
    __shared__ __bf16 xs[FMR * FXSS];
    __shared__ float  pbuf[4 * FMR];
    const int tid = threadIdx.x;
    const int w = tid >> 6, lane = tid & 63, lq = lane & 15, quad = lane >> 4;
    const int col = w * 16 + lq;
    const int n0 = blockIdx.x * 2;
    {
        const int* hb = hva + n0 * HL;
        const int* fb = haf + n0 * HL;
        #pragma unroll
        for (int i = 0; i < 13; ++i) {
            int t = i * 256 + tid;
            if (t < 2 * HL * 2 * 16) {
                int r = t >> 4, q = t & 15;
                bool va = (r < 2 * HL);
                int gr = va ? r : r - 2 * HL;
                int idx = va ? hb[gr] : fb[gr];
                const float* src = (va ? a2e : f2e) + (size_t)idx * DD + q * 4;
                float4 v = *(const float4*)src;
                bf16x4 pk = {(__bf16)v.x, (__bf16)v.y, (__bf16)v.z, (__bf16)v.w};
                *(bf16x4*)&xs[gr * FXSS + (va ? 0 : DD) + q * 4] = pk;
            }
        }
    }
    bf16x8 repf[2];
    #pragma unroll
    for (int t = 0; t < 2; ++t)
        #pragma unroll
        for (int j = 0; j < 8; ++j) repf[t][j] = (__bf16)0.f;
    if (lq < 2) {
        int nd = nodes[n0 + lq];
        const float* rp = v2e + (size_t)nd * DD;
        #pragma unroll
        for (int t = 0; t < 2; ++t) {
            float4 v0 = *(const float4*)(rp + t * 32 + quad * 8);
            float4 v1 = *(const float4*)(rp + t * 32 + quad * 8 + 4);
            repf[t] = (bf16x8){(__bf16)v0.x, (__bf16)v0.y, (__bf16)v0.z, (__bf16)v0.w,
                               (__bf16)v1.x, (__bf16)v1.y, (__bf16)v1.z, (__bf16)v1.w};
        }
    }
    const __bf16* fbp = wf + (size_t)(quad * 64 + col) * 64;
    bf16x8 b1f[4], b1u[2], b2f[2];
    #pragma unroll
    for (int t = 0; t < 4; ++t) b1f[t] = *(const bf16x8*)(fbp + t * 8);
    #pragma unroll
    for (int t = 0; t < 2; ++t) {
        b1u[t] = *(const bf16x8*)(fbp + 32 + t * 8);
        b2f[t] = *(const bf16x8*)(fbp + 48 + t * 8);
    }
    const float w3c = wsc[col];
    const float b1c = wsc[64 + col];
    const float b2c = wsc[128 + col];
    f32x4 rb = {0.f, 0.f, 0.f, 0.f};
    #pragma unroll
    for (int t = 0; t < 2; ++t)
        rb = __builtin_amdgcn_mfma_f32_16x16x32_bf16(repf[t], b1u[t], rb, 0, 0, 0);
    const float bias0 = __shfl(rb[0], lq) + b1c;
    const float bias1 = __shfl(rb[1], lq) + b1c;
    __syncthreads();
    f32x4 acc[FMT];
    #pragma unroll
    for (int mt = 0; mt < FMT; ++mt)
        #pragma unroll
        for (int r = 0; r < 4; ++r) {
            int gr = mt * 16 + quad * 4 + r;
            acc[mt][r] = (gr >= HL) ? bias1 : bias0;
        }
    #pragma unroll
    for (int t = 0; t < 4; ++t)
        #pragma unroll
        for (int mt = 0; mt < FMT; ++mt) {
            bf16x8 a = *(const bf16x8*)&xs[(mt * 16 + lq) * FXSS + t * 32 + quad * 8];
            acc[mt] = __builtin_amdgcn_mfma_f32_16x16x32_bf16(a, b1f[t], acc[mt], 0, 0, 0);
        }
    __syncthreads();
    #pragma unroll
    for (int mt = 0; mt < FMT; ++mt)
        #pragma unroll
        for (int r = 0; r < 4; ++r) {
            int gr = mt * 16 + quad * 4 + r;
            xs[gr * FXSS + DD + col] = (__bf16)fmaxf(acc[mt][r], 0.f);
        }
    __syncthreads();
    f32x4 a2[FMT];
    #pragma unroll
    for (int mt = 0; mt < FMT; ++mt) a2[mt] = (f32x4){b2c, b2c, b2c, b2c};
    #pragma unroll
    for (int t = 0; t < 2; ++t)
        #pragma unroll
        for (int mt = 0; mt < FMT; ++mt) {
            bf16x8 a = *(const bf16x8*)&xs[(mt * 16 + lq) * FXSS + DD + t * 32 + quad * 8];
            a2[mt] = __builtin_amdgcn_mfma_f32_16x16x32_bf16(a, b2f[t], a2[mt], 0, 0, 0);
        }
    #pragma unroll
    for (int mt = 0; mt < FMT; ++mt) {
        float p0 = fmaxf(a2[mt][0], 0.f) * w3c;
        float p1 = fmaxf(a2[mt][1], 0.f) * w3c;
        float p2 = fmaxf(a2[mt][2], 0.f) * w3c;
        float p3 = fmaxf(a2[mt][3], 0.f) * w3c;
        #pragma unroll
        for (int m = 1; m < 16; m <<= 1) {
            p0 += __shfl_xor(p0, m); p1 += __shfl_xor(p1, m);
            p2 += __shfl_xor(p2, m); p3 += __shfl_xor(p3, m);
        }
        if (lq == 0) {
            int rowb = mt * 16 + quad * 4;
            pbuf[w * FMR + rowb + 0] = p0; pbuf[w * FMR + rowb + 1] = p1;
            pbuf[w * FMR + rowb + 2] = p2; pbuf[w * FMR + rowb + 3] = p3;
        }
    }
    __syncthreads();
    const int n = w & 1, lh = w >> 1;
    float att;
    {
        float s = -3.0e38f;
        if (lane < HL) {
            int gr = n * HL + lane;
            s = pbuf[gr] + pbuf[FMR + gr] + pbuf[2 * FMR + gr] + pbuf[3 * FMR + gr];
        }
        float mx = s;
        #pragma unroll
        for (int m = 1; m < 64; m <<= 1) mx = fmaxf(mx, __shfl_xor(mx, m));
        float e = (lane < HL) ? __expf(s - mx) : 0.f;
        float sm = e;
        #pragma unroll
        for (int m = 1; m < 64; m <<= 1) sm += __shfl_xor(sm, m);
        att = e / sm;
    }
    {
        float o = 0.f;
        const int lb = lh * 25;
        #pragma unroll
        for (int i = 0; i < 25; ++i) {
            int l = lb + i;
            float av = __shfl(att, l);
            o = fmaf(av, (float)xs[(n * HL + l) * FXSS + lane], o);
        }
        float* op = (float*)&xs[(100 + w) * FXSS + DD];
        op[lane] = o;
    }
    __syncthreads();
    if (w < 2) {
        const float* p0 = (const float*)&xs[(100 + w) * FXSS + DD];
        const float* p1 = (const float*)&xs[(100 + w + 2) * FXSS + DD];
        out[(size_t)(n0 + w) * DD + lane] = p0[lane] + p1[lane];
    }
}

// ================================ host ==================================
extern "C" void kernel_launch(void* const* d_in, const int* in_sizes, int n_in,
                              void* d_out, int out_size, void* d_ws, size_t ws_size,
                              hipStream_t stream) {
    const int*   nodes = (const int*)d_in[0];
    const int*   hva   = (const int*)d_in[1];
    const int*   haf   = (const int*)d_in[2];
    const float* v2e   = (const float*)d_in[3];
    const float* a2e   = (const float*)d_in[4];
    const float* f2e   = (const float*)d_in[5];
    const float* W1    = (const float*)d_in[6];
    const float* b1    = (const float*)d_in[7];
    const float* W2    = (const float*)d_in[8];
    const float* b2    = (const float*)d_in[9];
    const float* w3    = (const float*)d_in[10];
    // d_in[11] = b3: softmax shift-invariant — unused.
    float* out = (float*)d_out;

    const int N  = in_sizes[0];            // 8192
    const int nA = in_sizes[4] / DD;       // 100000
    const int nF = in_sizes[5] / DD;       // 100000

    size_t offAE = 0;                                     // nA x 128 f16
    size_t offF2 = (offAE + (size_t)nA * 128 * 2 + 255) & ~(size_t)255;
    size_t offBA = (offF2 + (size_t)nF * DD * 2 + 255) & ~(size_t)255;
    size_t offWF = (offBA + (size_t)N * DD * 2 + 255) & ~(size_t)255;
    size_t offSC = offWF + 8 * 64 * 8 * 2;
    size_t need  = offSC + 128 * 4;

    if (ws_size >= need) {
        _Float16* AE  = (_Float16*)((char*)d_ws + offAE);
        _Float16* F2  = (_Float16*)((char*)d_ws + offF2);
        _Float16* ba  = (_Float16*)((char*)d_ws + offBA);
        _Float16* w2f = (_Float16*)((char*)d_ws + offWF);
        float*    wsc = (float*)((char*)d_ws + offSC);

        const int GAF = 320;               // grid-stride blocks per table
        const int GB  = (N + 63) / 64;
        prep_all_kernel<<<2 * GAF + GB + 1, 256, 0, stream>>>(
            nodes, v2e, a2e, f2e, W1, b1, W2, b2, w3,
            AE, F2, ba, w2f, wsc, nA, nF, N, GAF, GB);
        va_main_kernel<<<(N + 3) / 4, 256, 0, stream>>>(
            hva, haf, AE, F2, ba, w2f, wsc, out, N);
    } else {
        // workspace too small for precompute path — proven R6 fallback (33 KB)
        __bf16* wf  = (__bf16*)d_ws;
        float*  wsc = (float*)((char*)d_ws + 256 * 64 * 2);
        fb_prep_kernel<<<1, 256, 0, stream>>>(W1, W2, w3, b1, b2, wf, wsc);
        fb_agg_kernel<<<N / 2, 256, 0, stream>>>(nodes, hva, haf, v2e, a2e, f2e,
                                                 wf, wsc, out);
    }
}